// Round 9
// baseline (476.445 us; speedup 1.0000x reference)
//
#include <hip/hip_runtime.h>
#include <math.h>

#define BN_EPS 1e-5f
#define SCAN_CHUNK 4096

typedef __attribute__((ext_vector_type(8))) short bf16x8;
typedef __attribute__((ext_vector_type(4))) float f32x4;

// RNE fp32 -> bf16 (bit pattern)
__device__ __forceinline__ unsigned short f2bf(float f) {
    unsigned int u = __float_as_uint(f);
    u = (u + 0x7fffu + ((u >> 16) & 1u)) >> 16;
    return (unsigned short)u;
}
__device__ __forceinline__ float bflo(unsigned int u) { return __uint_as_float(u << 16); }
__device__ __forceinline__ float bfhi(unsigned int u) { return __uint_as_float(u & 0xffff0000u); }
__device__ __forceinline__ int ntl(const int* p) { return __builtin_nontemporal_load(p); }

// accumulate a bf16x2 word, optionally applying per-column BN affine + ReLU first
template<bool BNIN>
__device__ __forceinline__ void acc2(unsigned int u, float sc0, float sh0, float sc1, float sh1,
                                     float& a0, float& a1) {
    if constexpr (BNIN) {
        a0 += fmaxf(bflo(u) * sc0 + sh0, 0.f);
        a1 += fmaxf(bfhi(u) * sc1 + sh1, 0.f);
    } else {
        a0 += bflo(u);
        a1 += bfhi(u);
    }
}

// ---------------- fp32 -> bf16 bulk convert ----------------
__global__ void to_bf16_k(const float* __restrict__ in, unsigned short* __restrict__ out, int n4) {
    int i = blockIdx.x * blockDim.x + threadIdx.x;
    if (i >= n4) return;
    float4 v = ((const float4*)in)[i];
    ((ushort4*)out)[i] = make_ushort4(f2bf(v.x), f2bf(v.y), f2bf(v.z), f2bf(v.w));
}

// ---------------- XCD-sliced degree count (nt dst stream) ----------------
__global__ void count_edges_sliced_k(const int* __restrict__ dst, int E,
                                     int* __restrict__ cnt, int nper) {
    const int slice = blockIdx.x & 7;
    const int lo = slice * nper;
    const int hi = lo + nper;
    int i = (blockIdx.x >> 3) * blockDim.x + threadIdx.x;
    int stride = (gridDim.x >> 3) * blockDim.x;
    for (int e = i; e < E; e += stride) {
        int d = ntl(&dst[e]);
        if (d >= lo && d < hi) atomicAdd(&cnt[d], 1);
    }
}

// ---------------- hierarchical scan ----------------
__device__ __forceinline__ int wave_incl_scan(int v, int lane) {
#pragma unroll
    for (int d = 1; d < 64; d <<= 1) {
        int u = __shfl_up(v, d);
        if (lane >= d) v += u;
    }
    return v;
}

__global__ void block_sum_k(const int* __restrict__ cnt, int N, int* __restrict__ bsum) {
    const int t = threadIdx.x;
    const int base = blockIdx.x * SCAN_CHUNK;
    int s = 0;
    for (int i = t; i < SCAN_CHUNK; i += 256) {
        int idx = base + i;
        if (idx < N) s += ntl(&cnt[idx]);
    }
    const int lane = t & 63, wid = t >> 6;
#pragma unroll
    for (int d = 32; d; d >>= 1) s += __shfl_down(s, d);
    __shared__ int ws[4];
    if (lane == 0) ws[wid] = s;
    __syncthreads();
    if (t == 0) bsum[blockIdx.x] = ws[0] + ws[1] + ws[2] + ws[3];
}

// per-chunk local scan + inline exclusive scan of bsum; writes off/cursor/inv
__global__ void scan_write_k(const int* __restrict__ cnt, const int* __restrict__ bsum, int nb,
                             int N, int* __restrict__ off, int* __restrict__ cursor,
                             float* __restrict__ inv) {
    const int t = threadIdx.x;
    __shared__ int ws[4];
    __shared__ int base_s;
    if (t < 64) {
        int v = (t < nb) ? bsum[t] : 0;
        int incl = wave_incl_scan(v, t);
        if (t == blockIdx.x) base_s = incl - v;
    }
    const int base = blockIdx.x * SCAN_CHUNK;
    const int idx0 = base + t * 16;
    int pre[16];
    int s = 0;
#pragma unroll
    for (int j = 0; j < 16; ++j) {
        int i = idx0 + j;
        int c = (i < N) ? cnt[i] : 0;
        pre[j] = s;
        s += c;
    }
    const int lane = t & 63, wid = t >> 6;
    int incl = wave_incl_scan(s, lane);
    if (lane == 63) ws[wid] = incl;
    __syncthreads();
    if (t == 0) {
        int a = 0;
#pragma unroll
        for (int w = 0; w < 4; ++w) { int tmp = ws[w]; ws[w] = a; a += tmp; }
    }
    __syncthreads();
    const int tbase = base_s + (incl - s) + ws[wid];
#pragma unroll
    for (int j = 0; j < 16; ++j) {
        int i = idx0 + j;
        if (i < N) {
            int c = cnt[i];
            int o = tbase + pre[j];
            off[i] = o;
            cursor[i] = o;
            inv[i] = 1.0f / fmaxf((float)c, 1.0f);
        }
    }
}

// ---------------- XCD-sliced CSR fill (nt dst/src streams) ----------------
__global__ void csr_fill_sliced_k(const int* __restrict__ src, const int* __restrict__ dst,
                                  const int* __restrict__ off, int E,
                                  int* __restrict__ cursor, int* __restrict__ csr,
                                  float slice_scale) {
    const int slice = blockIdx.x & 7;
    const int g = blockIdx.x >> 3;
    const int ng = gridDim.x >> 3;
    int i = g * blockDim.x + threadIdx.x;
    int stride = ng * blockDim.x;
    for (int e = i; e < E; e += stride) {
        int d = ntl(&dst[e]);
        int o = off[d];
        int s = (int)((float)o * slice_scale);
        s = s > 7 ? 7 : s;
        if (s == slice) {
            int pos = atomicAdd(&cursor[d], 1);
            csr[pos] = ntl(&src[e]);
        }
    }
}

// ---------------- weight pre-pack into MFMA B-fragment order (bf16) ----------------
__global__ void wfrag_build_k(const float* __restrict__ Wl, const float* __restrict__ Wr,
                              int CIN, int KIT, unsigned short* __restrict__ wf) {
    int t = blockIdx.x * blockDim.x + threadIdx.x;
    int lane = t & 63;
    int q = t >> 6;
    if (q >= 8 * KIT) return;
    int kit = q % KIT;
    int ct = q / KIT;
    int col = ct * 16 + (lane & 15);
    bf16x8 v;
#pragma unroll
    for (int j = 0; j < 8; ++j) {
        int kg = kit * 32 + ((lane >> 4) << 3) + j;
        float f = (kg < CIN) ? Wl[(size_t)kg * 128 + col] : Wr[(size_t)(kg - CIN) * 128 + col];
        v[j] = (short)f2bf(f);
    }
    ((bf16x8*)wf)[q * 64 + lane] = v;
}

// ---------------- fused [BN0-on-read] gather-mean + MFMA gemm + BN stats ----------------
// outb[32x128] = bf16([mean_agg(f(feat)) | f(xin)] @ [Wl;Wr] + bl),
// f = identity (BNIN=false) or relu(bn(.)) with per-block sfin recomputed from stats8in.
// stats8out += column sum/sumsq of the fp32 pre-round outputs. csr read non-temporally
// (streaming) so feat rows keep L2 residency.
template<int CIN, bool BNIN>
__launch_bounds__(256)
__global__ void fused_sage_k(const unsigned short* __restrict__ feat,
                             const unsigned short* __restrict__ xin,
                             const int* __restrict__ csr, const int* __restrict__ off,
                             const int* __restrict__ endp, const float* __restrict__ inv,
                             const unsigned short* __restrict__ wfrag,
                             const float* __restrict__ bl,
                             const float* __restrict__ g, const float* __restrict__ be,
                             const float* __restrict__ stats8in,
                             unsigned short* __restrict__ outb,
                             float* __restrict__ stats8out, int N) {
    constexpr int KT = 2 * CIN;
    constexpr int KIT = KT / 32;
    __shared__ unsigned short sA[32 * KT];   // [row][k] bf16, XOR-swizzled by (row&7)<<4 bytes
    __shared__ float sfinS[256];             // scale[128], shift[128] (BNIN only)

    const int t = threadIdx.x;
    const int lane = t & 63, wave = t >> 6;
    const int rowbase = blockIdx.x * 32;
    const unsigned int* f32p = (const unsigned int*)feat;

    if constexpr (BNIN) {
        if (t < 128) {
            float s = 0.f, s2 = 0.f;
#pragma unroll
            for (int k = 0; k < 8; ++k) { s += stats8in[k * 256 + t]; s2 += stats8in[k * 256 + 128 + t]; }
            float mu = s / (float)N;
            float var = s2 / (float)N - mu * mu;
            float sc = g[t] * rsqrtf(var + BN_EPS);
            sfinS[t] = sc;
            sfinS[128 + t] = be[t] - mu * sc;
        }
        __syncthreads();
    }

    // ---- xin half: bf16 copy (+ optional BN affine + ReLU), 16B chunks
    constexpr int CH8 = CIN / 8;
    for (int i = t; i < 32 * CH8; i += 256) {
        int r = i / CH8, q = i % CH8;
        if (rowbase + r < N) {
            uint4 v = ((const uint4*)(xin + (size_t)(rowbase + r) * CIN))[q];
            if constexpr (BNIN) {
                unsigned int w[4] = {v.x, v.y, v.z, v.w};
#pragma unroll
                for (int j = 0; j < 4; ++j) {
                    int c = q * 8 + 2 * j;
                    float lo = fmaxf(bflo(w[j]) * sfinS[c]     + sfinS[128 + c],     0.f);
                    float hi = fmaxf(bfhi(w[j]) * sfinS[c + 1] + sfinS[128 + c + 1], 0.f);
                    w[j] = (unsigned int)f2bf(lo) | ((unsigned int)f2bf(hi) << 16);
                }
                v = make_uint4(w[0], w[1], w[2], w[3]);
            }
            int byte = ((r * KT + CIN + q * 8) * 2) ^ ((r & 7) << 4);
            *(uint4*)((char*)sA + byte) = v;
        }
    }

    // per-lane BN consts for the gather side (lane's columns are fixed)
    float sc0 = 1.f, sh0 = 0.f, sc1 = 1.f, sh1 = 0.f;
    if constexpr (BNIN) {
        int cc = (CIN == 128) ? (2 * lane) : (2 * (lane & 31));
        sc0 = sfinS[cc];     sh0 = sfinS[128 + cc];
        sc1 = sfinS[cc + 1]; sh1 = sfinS[128 + cc + 1];
    }

    // ---- agg half: wave gathers 8 rows' neighbor means (8 loads in flight)
#pragma unroll
    for (int rr = 0; rr < 8; ++rr) {
        int r = wave * 8 + rr;
        int n = rowbase + r;
        if (n < N) {
            const int o = off[n], eend = endp[n];
            float a0 = 0.f, a1 = 0.f, b0f = 0.f, b1f = 0.f;
            if constexpr (CIN == 128) {
                int e = o;
                for (; e + 7 < eend; e += 8) {
                    unsigned int u0 = f32p[(size_t)ntl(&csr[e])     * 64 + lane];
                    unsigned int u1 = f32p[(size_t)ntl(&csr[e + 1]) * 64 + lane];
                    unsigned int u2 = f32p[(size_t)ntl(&csr[e + 2]) * 64 + lane];
                    unsigned int u3 = f32p[(size_t)ntl(&csr[e + 3]) * 64 + lane];
                    unsigned int u4 = f32p[(size_t)ntl(&csr[e + 4]) * 64 + lane];
                    unsigned int u5 = f32p[(size_t)ntl(&csr[e + 5]) * 64 + lane];
                    unsigned int u6 = f32p[(size_t)ntl(&csr[e + 6]) * 64 + lane];
                    unsigned int u7 = f32p[(size_t)ntl(&csr[e + 7]) * 64 + lane];
                    acc2<BNIN>(u0, sc0, sh0, sc1, sh1, a0, a1);
                    acc2<BNIN>(u1, sc0, sh0, sc1, sh1, b0f, b1f);
                    acc2<BNIN>(u2, sc0, sh0, sc1, sh1, a0, a1);
                    acc2<BNIN>(u3, sc0, sh0, sc1, sh1, b0f, b1f);
                    acc2<BNIN>(u4, sc0, sh0, sc1, sh1, a0, a1);
                    acc2<BNIN>(u5, sc0, sh0, sc1, sh1, b0f, b1f);
                    acc2<BNIN>(u6, sc0, sh0, sc1, sh1, a0, a1);
                    acc2<BNIN>(u7, sc0, sh0, sc1, sh1, b0f, b1f);
                }
                for (; e + 3 < eend; e += 4) {
                    unsigned int u0 = f32p[(size_t)ntl(&csr[e])     * 64 + lane];
                    unsigned int u1 = f32p[(size_t)ntl(&csr[e + 1]) * 64 + lane];
                    unsigned int u2 = f32p[(size_t)ntl(&csr[e + 2]) * 64 + lane];
                    unsigned int u3 = f32p[(size_t)ntl(&csr[e + 3]) * 64 + lane];
                    acc2<BNIN>(u0, sc0, sh0, sc1, sh1, a0, a1);
                    acc2<BNIN>(u1, sc0, sh0, sc1, sh1, b0f, b1f);
                    acc2<BNIN>(u2, sc0, sh0, sc1, sh1, a0, a1);
                    acc2<BNIN>(u3, sc0, sh0, sc1, sh1, b0f, b1f);
                }
                for (; e < eend; ++e) {
                    unsigned int u = f32p[(size_t)ntl(&csr[e]) * 64 + lane];
                    acc2<BNIN>(u, sc0, sh0, sc1, sh1, a0, a1);
                }
                a0 += b0f; a1 += b1f;
                float iv = inv[n];
                unsigned int pk = (unsigned int)f2bf(a0 * iv) | ((unsigned int)f2bf(a1 * iv) << 16);
                int byte = ((r * KT + 2 * lane) * 2) ^ ((r & 7) << 4);
                *(unsigned int*)((char*)sA + byte) = pk;
            } else {
                // half-wave per neighbor: c = u32 col (32 per row), g2 = parity
                const int c = lane & 31, g2 = lane >> 5;
                int e = o + g2;
                for (; e + 14 < eend; e += 16) {
                    unsigned int u0 = f32p[(size_t)ntl(&csr[e])      * 32 + c];
                    unsigned int u1 = f32p[(size_t)ntl(&csr[e + 2])  * 32 + c];
                    unsigned int u2 = f32p[(size_t)ntl(&csr[e + 4])  * 32 + c];
                    unsigned int u3 = f32p[(size_t)ntl(&csr[e + 6])  * 32 + c];
                    unsigned int u4 = f32p[(size_t)ntl(&csr[e + 8])  * 32 + c];
                    unsigned int u5 = f32p[(size_t)ntl(&csr[e + 10]) * 32 + c];
                    unsigned int u6 = f32p[(size_t)ntl(&csr[e + 12]) * 32 + c];
                    unsigned int u7 = f32p[(size_t)ntl(&csr[e + 14]) * 32 + c];
                    acc2<false>(u0, 0, 0, 0, 0, a0, a1);
                    acc2<false>(u1, 0, 0, 0, 0, b0f, b1f);
                    acc2<false>(u2, 0, 0, 0, 0, a0, a1);
                    acc2<false>(u3, 0, 0, 0, 0, b0f, b1f);
                    acc2<false>(u4, 0, 0, 0, 0, a0, a1);
                    acc2<false>(u5, 0, 0, 0, 0, b0f, b1f);
                    acc2<false>(u6, 0, 0, 0, 0, a0, a1);
                    acc2<false>(u7, 0, 0, 0, 0, b0f, b1f);
                }
                for (; e + 6 < eend; e += 8) {
                    unsigned int u0 = f32p[(size_t)ntl(&csr[e])     * 32 + c];
                    unsigned int u1 = f32p[(size_t)ntl(&csr[e + 2]) * 32 + c];
                    unsigned int u2 = f32p[(size_t)ntl(&csr[e + 4]) * 32 + c];
                    unsigned int u3 = f32p[(size_t)ntl(&csr[e + 6]) * 32 + c];
                    acc2<false>(u0, 0, 0, 0, 0, a0, a1);
                    acc2<false>(u1, 0, 0, 0, 0, b0f, b1f);
                    acc2<false>(u2, 0, 0, 0, 0, a0, a1);
                    acc2<false>(u3, 0, 0, 0, 0, b0f, b1f);
                }
                for (; e < eend; e += 2) {
                    unsigned int u = f32p[(size_t)ntl(&csr[e]) * 32 + c];
                    acc2<false>(u, 0, 0, 0, 0, a0, a1);
                }
                a0 += b0f; a1 += b1f;
                a0 += __shfl_xor(a0, 32);
                a1 += __shfl_xor(a1, 32);
                if (g2 == 0) {
                    float iv = inv[n];
                    unsigned int pk = (unsigned int)f2bf(a0 * iv) | ((unsigned int)f2bf(a1 * iv) << 16);
                    int byte = ((r * KT + 2 * c) * 2) ^ ((r & 7) << 4);
                    *(unsigned int*)((char*)sA + byte) = pk;
                }
            }
        }
    }
    __syncthreads();

    // ---- MFMA K-loop
    f32x4 acc00 = {0.f,0.f,0.f,0.f}, acc01 = acc00, acc10 = acc00, acc11 = acc00;
    const int koff = (lane >> 4) << 4;
    const int swz = (lane & 7) << 4;
    const int base0 = (lane & 15) * KT * 2 + koff;
    const int base1 = (16 + (lane & 15)) * KT * 2 + koff;
    const bf16x8* wf8 = (const bf16x8*)wfrag;
    const int bq0 = (wave * 2 + 0) * KIT;
    const int bq1 = (wave * 2 + 1) * KIT;

#pragma unroll
    for (int kit = 0; kit < KIT; ++kit) {
        bf16x8 fa0 = *(const bf16x8*)((const char*)sA + ((base0 + kit * 64) ^ swz));
        bf16x8 fa1 = *(const bf16x8*)((const char*)sA + ((base1 + kit * 64) ^ swz));
        bf16x8 fb0 = wf8[(bq0 + kit) * 64 + lane];
        bf16x8 fb1 = wf8[(bq1 + kit) * 64 + lane];
        acc00 = __builtin_amdgcn_mfma_f32_16x16x32_bf16(fa0, fb0, acc00, 0, 0, 0);
        acc01 = __builtin_amdgcn_mfma_f32_16x16x32_bf16(fa0, fb1, acc01, 0, 0, 0);
        acc10 = __builtin_amdgcn_mfma_f32_16x16x32_bf16(fa1, fb0, acc10, 0, 0, 0);
        acc11 = __builtin_amdgcn_mfma_f32_16x16x32_bf16(fa1, fb1, acc11, 0, 0, 0);
    }

    // ---- epilogue: bf16 store + fp32 col stats. C/D layout col=lane&15, row=(lane>>4)*4+reg.
    const int c0 = wave * 32 + (lane & 15);
    const int c1 = c0 + 16;
    const float b0 = bl[c0], b1 = bl[c1];
    float sum0 = 0.f, sq0 = 0.f, sum1 = 0.f, sq1 = 0.f;
    const int row0base = rowbase + ((lane >> 4) << 2);
#pragma unroll
    for (int r = 0; r < 4; ++r) {
        int row0 = row0base + r, row1 = row0 + 16;
        float v00 = acc00[r] + b0, v01 = acc01[r] + b1;
        float v10 = acc10[r] + b0, v11 = acc11[r] + b1;
        if (row0 < N) {
            outb[(size_t)row0 * 128 + c0] = f2bf(v00);
            outb[(size_t)row0 * 128 + c1] = f2bf(v01);
            sum0 += v00; sq0 += v00 * v00; sum1 += v01; sq1 += v01 * v01;
        }
        if (row1 < N) {
            outb[(size_t)row1 * 128 + c0] = f2bf(v10);
            outb[(size_t)row1 * 128 + c1] = f2bf(v11);
            sum0 += v10; sq0 += v10 * v10; sum1 += v11; sq1 += v11 * v11;
        }
    }
#pragma unroll
    for (int m = 16; m < 64; m <<= 1) {
        sum0 += __shfl_xor(sum0, m); sq0 += __shfl_xor(sq0, m);
        sum1 += __shfl_xor(sum1, m); sq1 += __shfl_xor(sq1, m);
    }
    if (lane < 16) {
        float* st = stats8out + (blockIdx.x & 7) * 256;
        atomicAdd(&st[c0], sum0);
        atomicAdd(&st[128 + c0], sq0);
        atomicAdd(&st[c1], sum1);
        atomicAdd(&st[128 + c1], sq1);
    }
}

// ---------------- BN finalize from 8 sliced stat buffers ----------------
__global__ void bn_finalize8_k(const float* __restrict__ g, const float* __restrict__ be,
                               const float* __restrict__ stats8, float* __restrict__ sfin, int N) {
    int c = threadIdx.x;
    if (c < 128) {
        float s = 0.f, s2 = 0.f;
#pragma unroll
        for (int k = 0; k < 8; ++k) { s += stats8[k * 256 + c]; s2 += stats8[k * 256 + 128 + c]; }
        float mu = s / (float)N;
        float var = s2 / (float)N - mu * mu;
        float sc = g[c] * rsqrtf(var + BN_EPS);
        sfin[c] = sc;
        sfin[128 + c] = be[c] - mu * sc;
    }
}

// ---------------- BN apply + ReLU + bf16 in-place + p = h.Wl2 ----------------
__global__ void bn_apply_p_k(unsigned short* __restrict__ hb, const float* __restrict__ sfin,
                             const float* __restrict__ Wl2, float* __restrict__ p, int N) {
    const int lane = threadIdx.x & 63;
    const int n = (int)((blockIdx.x * (long long)blockDim.x + threadIdx.x) >> 6);
    if (n >= N) return;
    const float2 sc = ((const float2*)sfin)[lane];
    const float2 sh = ((const float2*)(sfin + 128))[lane];
    const float2 w  = ((const float2*)Wl2)[lane];
    unsigned int u = ((unsigned int*)(hb + (size_t)n * 128))[lane];
    float vx = fmaxf(bflo(u) * sc.x + sh.x, 0.f);
    float vy = fmaxf(bfhi(u) * sc.y + sh.y, 0.f);
    ((unsigned int*)(hb + (size_t)n * 128))[lane] = (unsigned int)f2bf(vx) | ((unsigned int)f2bf(vy) << 16);
    float s = vx * w.x + vy * w.y;
#pragma unroll
    for (int o = 32; o; o >>= 1) s += __shfl_down(s, o);
    if (lane == 0) p[n] = s;
}

// ---------------- layer 2 final ----------------
__global__ void layer2_final_k(const unsigned short* __restrict__ hb, const float* __restrict__ p,
                               const int* __restrict__ csr, const int* __restrict__ off,
                               const int* __restrict__ endp, const float* __restrict__ inv,
                               const float* __restrict__ Wr2, const float* __restrict__ bl2,
                               const float* __restrict__ wF, const float* __restrict__ bF,
                               float* __restrict__ out, int N) {
    const int lane = threadIdx.x & 63;
    const int n = (int)((blockIdx.x * (long long)blockDim.x + threadIdx.x) >> 6);
    if (n >= N) return;
    float2 w = ((const float2*)Wr2)[lane];
    unsigned int u = ((const unsigned int*)(hb + (size_t)n * 128))[lane];
    float dotp = bflo(u) * w.x + bfhi(u) * w.y;
    float ps = 0.f;
    const int o = off[n], e_end = endp[n];
    for (int e = o + lane; e < e_end; e += 64) ps += p[ntl(&csr[e])];
    float s = dotp + ps * inv[n];
#pragma unroll
    for (int ow = 32; ow; ow >>= 1) s += __shfl_down(s, ow);
    if (lane == 0) {
        float z = (s + bl2[0]) * wF[0] + bF[0];
        out[n] = 1.f / (1.f + expf(-z));
    }
}

extern "C" void kernel_launch(void* const* d_in, const int* in_sizes, int n_in,
                              void* d_out, int out_size, void* d_ws, size_t ws_size,
                              hipStream_t stream) {
    const float* x   = (const float*)d_in[0];
    const int*   ei  = (const int*)d_in[1];
    const int E = in_sizes[1] / 2;
    const int N = in_sizes[0] / 64;
    const int* src = ei;
    const int* dst = ei + E;
    const float* Wl0 = (const float*)d_in[2];
    const float* bl0 = (const float*)d_in[3];
    const float* Wr0 = (const float*)d_in[4];
    const float* Wl1 = (const float*)d_in[5];
    const float* bl1 = (const float*)d_in[6];
    const float* Wr1 = (const float*)d_in[7];
    const float* Wl2 = (const float*)d_in[8];
    const float* bl2 = (const float*)d_in[9];
    const float* Wr2 = (const float*)d_in[10];
    const float* g0  = (const float*)d_in[11];
    const float* be0 = (const float*)d_in[12];
    const float* g1  = (const float*)d_in[13];
    const float* be1 = (const float*)d_in[14];
    const float* wF  = (const float*)d_in[15];
    const float* bF  = (const float*)d_in[16];

    char* wp = (char*)d_ws;
    unsigned short* h0   = (unsigned short*)wp;  wp += (size_t)N * 128 * 2;  // layer-0 out bf16 (pre-BN)
    unsigned short* h1   = (unsigned short*)wp;  wp += (size_t)N * 128 * 2;  // layer-1 out bf16
    unsigned short* xb   = (unsigned short*)wp;  wp += (size_t)N * 64 * 2;   // x bf16
    int*   cnt    = (int*)wp;    wp += (size_t)N * 4;
    int*   off    = (int*)wp;    wp += (size_t)N * 4;
    int*   cursor = (int*)wp;    wp += (size_t)N * 4;
    float* inv    = (float*)wp;  wp += (size_t)N * 4;
    int*   csr    = (int*)wp;    wp += (size_t)E * 4;
    float* stats8a = (float*)wp; wp += 2048 * 4;
    float* stats8b = (float*)wp; wp += 2048 * 4;
    float* sfin1   = (float*)wp; wp += 256 * 4;
    int*   bsum    = (int*)wp;   wp += 64 * 4;
    unsigned short* wf0 = (unsigned short*)wp; wp += 8 * 4 * 64 * 8 * 2;
    unsigned short* wf1 = (unsigned short*)wp; wp += 8 * 8 * 64 * 8 * 2;
    float* p = (float*)cnt;   // alias: cnt dead after scan/csr-fill
    float* out = (float*)d_out;

    const int gemm_grid = (N + 31) / 32;
    const int wave_grid = (N + 3) / 4;
    const int nb = (N + SCAN_CHUNK - 1) / SCAN_CHUNK;

    // ---- prep: weights, x->bf16, zero stats (stats8a+stats8b contiguous)
    wfrag_build_k<<<(8 * 4 * 64 + 255) / 256, 256, 0, stream>>>(Wl0, Wr0, 64, 4, wf0);
    wfrag_build_k<<<(8 * 8 * 64 + 255) / 256, 256, 0, stream>>>(Wl1, Wr1, 128, 8, wf1);
    to_bf16_k<<<(N * 16 + 255) / 256, 256, 0, stream>>>(x, xb, N * 16);
    hipMemsetAsync(stats8a, 0, (2048 + 2048) * sizeof(float), stream);

    // ---- CSR build
    hipMemsetAsync(cnt, 0, (size_t)N * sizeof(int), stream);
    count_edges_sliced_k<<<2048, 256, 0, stream>>>(dst, E, cnt, (N + 7) / 8);
    block_sum_k<<<nb, 256, 0, stream>>>(cnt, N, bsum);
    scan_write_k<<<nb, 256, 0, stream>>>(cnt, bsum, nb, N, off, cursor, inv);
    csr_fill_sliced_k<<<2048, 256, 0, stream>>>(src, dst, off, E, cursor, csr, 8.0f / (float)E);

    // ---- layer 0: xb -> h0 (raw, pre-BN)
    fused_sage_k<64, false><<<gemm_grid, 256, 0, stream>>>(
        xb, xb, csr, off, cursor, inv, wf0, bl0, nullptr, nullptr, nullptr, h0, stats8a, N);

    // ---- layer 1: h0 -> h1, BN0+ReLU applied on the fly (sfin0 from stats8a per block)
    fused_sage_k<128, true><<<gemm_grid, 256, 0, stream>>>(
        h0, h0, csr, off, cursor, inv, wf1, bl1, g0, be0, stats8a, h1, stats8b, N);

    // ---- BN1 finalize + apply + p = relu(bn(h1)).Wl2
    bn_finalize8_k<<<1, 128, 0, stream>>>(g1, be1, stats8b, sfin1, N);
    bn_apply_p_k<<<wave_grid, 256, 0, stream>>>(h1, sfin1, Wl2, p, N);

    // ---- layer 2 via scalar trick
    layer2_final_k<<<wave_grid, 256, 0, stream>>>(h1, p, csr, off, cursor, inv,
                                                  Wr2, bl2, wF, bF, out, N);
}

// Round 10
// 391.584 us; speedup vs baseline: 1.2167x; 1.2167x over previous
//
#include <hip/hip_runtime.h>
#include <math.h>

#define BN_EPS 1e-5f
#define SCAN_CHUNK 4096
#define BCHUNK 2048

typedef __attribute__((ext_vector_type(8))) short bf16x8;
typedef __attribute__((ext_vector_type(4))) float f32x4;

// RNE fp32 -> bf16 (bit pattern)
__device__ __forceinline__ unsigned short f2bf(float f) {
    unsigned int u = __float_as_uint(f);
    u = (u + 0x7fffu + ((u >> 16) & 1u)) >> 16;
    return (unsigned short)u;
}
__device__ __forceinline__ float bflo(unsigned int u) { return __uint_as_float(u << 16); }
__device__ __forceinline__ float bfhi(unsigned int u) { return __uint_as_float(u & 0xffff0000u); }

// accumulate a bf16x2 word, optionally applying per-column BN affine + ReLU first
template<bool BNIN>
__device__ __forceinline__ void acc2(unsigned int u, float sc0, float sh0, float sc1, float sh1,
                                     float& a0, float& a1) {
    if constexpr (BNIN) {
        a0 += fmaxf(bflo(u) * sc0 + sh0, 0.f);
        a1 += fmaxf(bfhi(u) * sc1 + sh1, 0.f);
    } else {
        a0 += bflo(u);
        a1 += bfhi(u);
    }
}

// ---------------- fp32 -> bf16 bulk convert ----------------
__global__ void to_bf16_k(const float* __restrict__ in, unsigned short* __restrict__ out, int n4) {
    int i = blockIdx.x * blockDim.x + threadIdx.x;
    if (i >= n4) return;
    float4 v = ((const float4*)in)[i];
    ((ushort4*)out)[i] = make_ushort4(f2bf(v.x), f2bf(v.y), f2bf(v.z), f2bf(v.w));
}

// ---------------- XCD-sliced degree count ----------------
__global__ void count_edges_sliced_k(const int* __restrict__ dst, int E,
                                     int* __restrict__ cnt, int nper) {
    const int slice = blockIdx.x & 7;
    const int lo = slice * nper;
    const int hi = lo + nper;
    int i = (blockIdx.x >> 3) * blockDim.x + threadIdx.x;
    int stride = (gridDim.x >> 3) * blockDim.x;
    for (int e = i; e < E; e += stride) {
        int d = dst[e];
        if (d >= lo && d < hi) atomicAdd(&cnt[d], 1);
    }
}

// ---------------- hierarchical scan ----------------
__device__ __forceinline__ int wave_incl_scan(int v, int lane) {
#pragma unroll
    for (int d = 1; d < 64; d <<= 1) {
        int u = __shfl_up(v, d);
        if (lane >= d) v += u;
    }
    return v;
}

__global__ void block_sum_k(const int* __restrict__ cnt, int N, int* __restrict__ bsum) {
    const int t = threadIdx.x;
    const int base = blockIdx.x * SCAN_CHUNK;
    int s = 0;
    for (int i = t; i < SCAN_CHUNK; i += 256) {
        int idx = base + i;
        if (idx < N) s += cnt[idx];
    }
    const int lane = t & 63, wid = t >> 6;
#pragma unroll
    for (int d = 32; d; d >>= 1) s += __shfl_down(s, d);
    __shared__ int ws[4];
    if (lane == 0) ws[wid] = s;
    __syncthreads();
    if (t == 0) bsum[blockIdx.x] = ws[0] + ws[1] + ws[2] + ws[3];
}

// per-chunk local scan + inline exclusive scan of bsum; writes off/cursor/inv
__global__ void scan_write_k(const int* __restrict__ cnt, const int* __restrict__ bsum, int nb,
                             int N, int* __restrict__ off, int* __restrict__ cursor,
                             float* __restrict__ inv) {
    const int t = threadIdx.x;
    __shared__ int ws[4];
    __shared__ int base_s;
    if (t < 64) {
        int v = (t < nb) ? bsum[t] : 0;
        int incl = wave_incl_scan(v, t);
        if (t == blockIdx.x) base_s = incl - v;
    }
    const int base = blockIdx.x * SCAN_CHUNK;
    const int idx0 = base + t * 16;
    int pre[16];
    int s = 0;
#pragma unroll
    for (int j = 0; j < 16; ++j) {
        int i = idx0 + j;
        int c = (i < N) ? cnt[i] : 0;
        pre[j] = s;
        s += c;
    }
    const int lane = t & 63, wid = t >> 6;
    int incl = wave_incl_scan(s, lane);
    if (lane == 63) ws[wid] = incl;
    __syncthreads();
    if (t == 0) {
        int a = 0;
#pragma unroll
        for (int w = 0; w < 4; ++w) { int tmp = ws[w]; ws[w] = a; a += tmp; }
    }
    __syncthreads();
    const int tbase = base_s + (incl - s) + ws[wid];
#pragma unroll
    for (int j = 0; j < 16; ++j) {
        int i = idx0 + j;
        if (i < N) {
            int c = cnt[i];
            int o = tbase + pre[j];
            off[i] = o;
            cursor[i] = o;
            inv[i] = 1.0f / fmaxf((float)c, 1.0f);
        }
    }
}

// ---------------- bucket bases from off[] (edge-space boundaries of dst-range buckets) ----
__global__ void bucket_base_k(const int* __restrict__ off, int N, int E, int nper,
                              int* __restrict__ bbase, int* __restrict__ bcur) {
    int b = threadIdx.x;
    if (b < 9) {
        int node = b * nper;
        int v = (node < N) ? off[node] : E;
        bbase[b] = v;
        if (b < 8) bcur[b] = v;
    }
}

// ---------------- bucketize: partition edge list into 8 dst-range buckets ----------------
// LDS-staged so global writes are coalesced segment flushes. ebuf[i] = (src, dst).
__global__ void bucketize_k(const int* __restrict__ src, const int* __restrict__ dst,
                            int E, int nper, int* __restrict__ bcur, uint2* __restrict__ ebuf) {
    __shared__ int hist[8], lofs[8], gofs[8], cpos[8];
    __shared__ uint2 buf[BCHUNK];
    const int t = threadIdx.x;
    const int base = blockIdx.x * BCHUNK;
    if (base >= E) return;
    const int chunk = min(BCHUNK, E - base);

    if (t < 8) hist[t] = 0;
    __syncthreads();

    int my_d[8], my_s[8], my_b[8];
#pragma unroll
    for (int j = 0; j < 8; ++j) {
        int e = base + j * 256 + t;
        if (j * 256 + t < chunk) {
            my_d[j] = dst[e];
            my_s[j] = src[e];
            my_b[j] = my_d[j] / nper;
            atomicAdd(&hist[my_b[j]], 1);
        } else my_b[j] = -1;
    }
    __syncthreads();
    if (t == 0) {
        int a = 0;
#pragma unroll
        for (int b = 0; b < 8; ++b) { lofs[b] = a; cpos[b] = a; a += hist[b]; }
    }
    __syncthreads();
    if (t < 8) gofs[t] = hist[t] ? atomicAdd(&bcur[t], hist[t]) : 0;
    __syncthreads();
#pragma unroll
    for (int j = 0; j < 8; ++j) {
        if (my_b[j] >= 0) {
            int pos = atomicAdd(&cpos[my_b[j]], 1);
            buf[pos] = make_uint2((unsigned)my_s[j], (unsigned)my_d[j]);
        }
    }
    __syncthreads();
    for (int i = t; i < chunk; i += 256) {
        int b = 0;
#pragma unroll
        for (int bb = 1; bb < 8; ++bb) if (i >= lofs[bb]) b = bb;
        ebuf[gofs[b] + (i - lofs[b])] = buf[i];
    }
}

// ---------------- CSR fill from buckets: slice s works entirely in one XCD's L2 ----------
__global__ void csr_fill_bucketed_k(const uint2* __restrict__ ebuf, const int* __restrict__ bbase,
                                    int* __restrict__ cursor, int* __restrict__ csr) {
    const int s = blockIdx.x & 7;
    const int g = blockIdx.x >> 3;
    const int ng = gridDim.x >> 3;
    const int lo = bbase[s], hi = bbase[s + 1];
    for (int i = lo + g * blockDim.x + threadIdx.x; i < hi; i += ng * blockDim.x) {
        uint2 v = ebuf[i];
        int pos = atomicAdd(&cursor[(int)v.y], 1);
        csr[pos] = (int)v.x;
    }
}

// ---------------- weight pre-pack into MFMA B-fragment order (bf16) ----------------
__global__ void wfrag_build_k(const float* __restrict__ Wl, const float* __restrict__ Wr,
                              int CIN, int KIT, unsigned short* __restrict__ wf) {
    int t = blockIdx.x * blockDim.x + threadIdx.x;
    int lane = t & 63;
    int q = t >> 6;
    if (q >= 8 * KIT) return;
    int kit = q % KIT;
    int ct = q / KIT;
    int col = ct * 16 + (lane & 15);
    bf16x8 v;
#pragma unroll
    for (int j = 0; j < 8; ++j) {
        int kg = kit * 32 + ((lane >> 4) << 3) + j;
        float f = (kg < CIN) ? Wl[(size_t)kg * 128 + col] : Wr[(size_t)(kg - CIN) * 128 + col];
        v[j] = (short)f2bf(f);
    }
    ((bf16x8*)wf)[q * 64 + lane] = v;
}

// ---------------- fused [BN0-on-read] gather-mean + MFMA gemm + BN stats ----------------
template<int CIN, bool BNIN>
__launch_bounds__(256)
__global__ void fused_sage_k(const unsigned short* __restrict__ feat,
                             const unsigned short* __restrict__ xin,
                             const int* __restrict__ csr, const int* __restrict__ off,
                             const int* __restrict__ endp, const float* __restrict__ inv,
                             const unsigned short* __restrict__ wfrag,
                             const float* __restrict__ bl,
                             const float* __restrict__ g, const float* __restrict__ be,
                             const float* __restrict__ stats8in,
                             unsigned short* __restrict__ outb,
                             float* __restrict__ stats8out, int N) {
    constexpr int KT = 2 * CIN;
    constexpr int KIT = KT / 32;
    __shared__ unsigned short sA[32 * KT];   // [row][k] bf16, XOR-swizzled by (row&7)<<4 bytes
    __shared__ float sfinS[256];             // scale[128], shift[128] (BNIN only)

    const int t = threadIdx.x;
    const int lane = t & 63, wave = t >> 6;
    const int rowbase = blockIdx.x * 32;
    const unsigned int* f32p = (const unsigned int*)feat;

    if constexpr (BNIN) {
        if (t < 128) {
            float s = 0.f, s2 = 0.f;
#pragma unroll
            for (int k = 0; k < 8; ++k) { s += stats8in[k * 256 + t]; s2 += stats8in[k * 256 + 128 + t]; }
            float mu = s / (float)N;
            float var = s2 / (float)N - mu * mu;
            float sc = g[t] * rsqrtf(var + BN_EPS);
            sfinS[t] = sc;
            sfinS[128 + t] = be[t] - mu * sc;
        }
        __syncthreads();
    }

    // ---- xin half: bf16 copy (+ optional BN affine + ReLU), 16B chunks
    constexpr int CH8 = CIN / 8;
    for (int i = t; i < 32 * CH8; i += 256) {
        int r = i / CH8, q = i % CH8;
        if (rowbase + r < N) {
            uint4 v = ((const uint4*)(xin + (size_t)(rowbase + r) * CIN))[q];
            if constexpr (BNIN) {
                unsigned int w[4] = {v.x, v.y, v.z, v.w};
#pragma unroll
                for (int j = 0; j < 4; ++j) {
                    int c = q * 8 + 2 * j;
                    float lo = fmaxf(bflo(w[j]) * sfinS[c]     + sfinS[128 + c],     0.f);
                    float hi = fmaxf(bfhi(w[j]) * sfinS[c + 1] + sfinS[128 + c + 1], 0.f);
                    w[j] = (unsigned int)f2bf(lo) | ((unsigned int)f2bf(hi) << 16);
                }
                v = make_uint4(w[0], w[1], w[2], w[3]);
            }
            int byte = ((r * KT + CIN + q * 8) * 2) ^ ((r & 7) << 4);
            *(uint4*)((char*)sA + byte) = v;
        }
    }

    // per-lane BN consts for the gather side (lane's columns are fixed)
    float sc0 = 1.f, sh0 = 0.f, sc1 = 1.f, sh1 = 0.f;
    if constexpr (BNIN) {
        int cc = (CIN == 128) ? (2 * lane) : (2 * (lane & 31));
        sc0 = sfinS[cc];     sh0 = sfinS[128 + cc];
        sc1 = sfinS[cc + 1]; sh1 = sfinS[128 + cc + 1];
    }

    // ---- agg half: wave gathers 8 rows' neighbor means (8 loads in flight)
#pragma unroll
    for (int rr = 0; rr < 8; ++rr) {
        int r = wave * 8 + rr;
        int n = rowbase + r;
        if (n < N) {
            const int o = off[n], eend = endp[n];
            float a0 = 0.f, a1 = 0.f, b0f = 0.f, b1f = 0.f;
            if constexpr (CIN == 128) {
                int e = o;
                for (; e + 7 < eend; e += 8) {
                    unsigned int u0 = f32p[(size_t)csr[e]     * 64 + lane];
                    unsigned int u1 = f32p[(size_t)csr[e + 1] * 64 + lane];
                    unsigned int u2 = f32p[(size_t)csr[e + 2] * 64 + lane];
                    unsigned int u3 = f32p[(size_t)csr[e + 3] * 64 + lane];
                    unsigned int u4 = f32p[(size_t)csr[e + 4] * 64 + lane];
                    unsigned int u5 = f32p[(size_t)csr[e + 5] * 64 + lane];
                    unsigned int u6 = f32p[(size_t)csr[e + 6] * 64 + lane];
                    unsigned int u7 = f32p[(size_t)csr[e + 7] * 64 + lane];
                    acc2<BNIN>(u0, sc0, sh0, sc1, sh1, a0, a1);
                    acc2<BNIN>(u1, sc0, sh0, sc1, sh1, b0f, b1f);
                    acc2<BNIN>(u2, sc0, sh0, sc1, sh1, a0, a1);
                    acc2<BNIN>(u3, sc0, sh0, sc1, sh1, b0f, b1f);
                    acc2<BNIN>(u4, sc0, sh0, sc1, sh1, a0, a1);
                    acc2<BNIN>(u5, sc0, sh0, sc1, sh1, b0f, b1f);
                    acc2<BNIN>(u6, sc0, sh0, sc1, sh1, a0, a1);
                    acc2<BNIN>(u7, sc0, sh0, sc1, sh1, b0f, b1f);
                }
                for (; e + 3 < eend; e += 4) {
                    unsigned int u0 = f32p[(size_t)csr[e]     * 64 + lane];
                    unsigned int u1 = f32p[(size_t)csr[e + 1] * 64 + lane];
                    unsigned int u2 = f32p[(size_t)csr[e + 2] * 64 + lane];
                    unsigned int u3 = f32p[(size_t)csr[e + 3] * 64 + lane];
                    acc2<BNIN>(u0, sc0, sh0, sc1, sh1, a0, a1);
                    acc2<BNIN>(u1, sc0, sh0, sc1, sh1, b0f, b1f);
                    acc2<BNIN>(u2, sc0, sh0, sc1, sh1, a0, a1);
                    acc2<BNIN>(u3, sc0, sh0, sc1, sh1, b0f, b1f);
                }
                for (; e < eend; ++e) {
                    unsigned int u = f32p[(size_t)csr[e] * 64 + lane];
                    acc2<BNIN>(u, sc0, sh0, sc1, sh1, a0, a1);
                }
                a0 += b0f; a1 += b1f;
                float iv = inv[n];
                unsigned int pk = (unsigned int)f2bf(a0 * iv) | ((unsigned int)f2bf(a1 * iv) << 16);
                int byte = ((r * KT + 2 * lane) * 2) ^ ((r & 7) << 4);
                *(unsigned int*)((char*)sA + byte) = pk;
            } else {
                // half-wave per neighbor: c = u32 col (32 per row), g2 = parity
                const int c = lane & 31, g2 = lane >> 5;
                int e = o + g2;
                for (; e + 14 < eend; e += 16) {
                    unsigned int u0 = f32p[(size_t)csr[e]      * 32 + c];
                    unsigned int u1 = f32p[(size_t)csr[e + 2]  * 32 + c];
                    unsigned int u2 = f32p[(size_t)csr[e + 4]  * 32 + c];
                    unsigned int u3 = f32p[(size_t)csr[e + 6]  * 32 + c];
                    unsigned int u4 = f32p[(size_t)csr[e + 8]  * 32 + c];
                    unsigned int u5 = f32p[(size_t)csr[e + 10] * 32 + c];
                    unsigned int u6 = f32p[(size_t)csr[e + 12] * 32 + c];
                    unsigned int u7 = f32p[(size_t)csr[e + 14] * 32 + c];
                    acc2<false>(u0, 0, 0, 0, 0, a0, a1);
                    acc2<false>(u1, 0, 0, 0, 0, b0f, b1f);
                    acc2<false>(u2, 0, 0, 0, 0, a0, a1);
                    acc2<false>(u3, 0, 0, 0, 0, b0f, b1f);
                    acc2<false>(u4, 0, 0, 0, 0, a0, a1);
                    acc2<false>(u5, 0, 0, 0, 0, b0f, b1f);
                    acc2<false>(u6, 0, 0, 0, 0, a0, a1);
                    acc2<false>(u7, 0, 0, 0, 0, b0f, b1f);
                }
                for (; e + 6 < eend; e += 8) {
                    unsigned int u0 = f32p[(size_t)csr[e]     * 32 + c];
                    unsigned int u1 = f32p[(size_t)csr[e + 2] * 32 + c];
                    unsigned int u2 = f32p[(size_t)csr[e + 4] * 32 + c];
                    unsigned int u3 = f32p[(size_t)csr[e + 6] * 32 + c];
                    acc2<false>(u0, 0, 0, 0, 0, a0, a1);
                    acc2<false>(u1, 0, 0, 0, 0, b0f, b1f);
                    acc2<false>(u2, 0, 0, 0, 0, a0, a1);
                    acc2<false>(u3, 0, 0, 0, 0, b0f, b1f);
                }
                for (; e < eend; e += 2) {
                    unsigned int u = f32p[(size_t)csr[e] * 32 + c];
                    acc2<false>(u, 0, 0, 0, 0, a0, a1);
                }
                a0 += b0f; a1 += b1f;
                a0 += __shfl_xor(a0, 32);
                a1 += __shfl_xor(a1, 32);
                if (g2 == 0) {
                    float iv = inv[n];
                    unsigned int pk = (unsigned int)f2bf(a0 * iv) | ((unsigned int)f2bf(a1 * iv) << 16);
                    int byte = ((r * KT + 2 * c) * 2) ^ ((r & 7) << 4);
                    *(unsigned int*)((char*)sA + byte) = pk;
                }
            }
        }
    }
    __syncthreads();

    // ---- MFMA K-loop
    f32x4 acc00 = {0.f,0.f,0.f,0.f}, acc01 = acc00, acc10 = acc00, acc11 = acc00;
    const int koff = (lane >> 4) << 4;
    const int swz = (lane & 7) << 4;
    const int base0 = (lane & 15) * KT * 2 + koff;
    const int base1 = (16 + (lane & 15)) * KT * 2 + koff;
    const bf16x8* wf8 = (const bf16x8*)wfrag;
    const int bq0 = (wave * 2 + 0) * KIT;
    const int bq1 = (wave * 2 + 1) * KIT;

#pragma unroll
    for (int kit = 0; kit < KIT; ++kit) {
        bf16x8 fa0 = *(const bf16x8*)((const char*)sA + ((base0 + kit * 64) ^ swz));
        bf16x8 fa1 = *(const bf16x8*)((const char*)sA + ((base1 + kit * 64) ^ swz));
        bf16x8 fb0 = wf8[(bq0 + kit) * 64 + lane];
        bf16x8 fb1 = wf8[(bq1 + kit) * 64 + lane];
        acc00 = __builtin_amdgcn_mfma_f32_16x16x32_bf16(fa0, fb0, acc00, 0, 0, 0);
        acc01 = __builtin_amdgcn_mfma_f32_16x16x32_bf16(fa0, fb1, acc01, 0, 0, 0);
        acc10 = __builtin_amdgcn_mfma_f32_16x16x32_bf16(fa1, fb0, acc10, 0, 0, 0);
        acc11 = __builtin_amdgcn_mfma_f32_16x16x32_bf16(fa1, fb1, acc11, 0, 0, 0);
    }

    // ---- epilogue: bf16 store + fp32 col stats. C/D layout col=lane&15, row=(lane>>4)*4+reg.
    const int c0 = wave * 32 + (lane & 15);
    const int c1 = c0 + 16;
    const float b0 = bl[c0], b1 = bl[c1];
    float sum0 = 0.f, sq0 = 0.f, sum1 = 0.f, sq1 = 0.f;
    const int row0base = rowbase + ((lane >> 4) << 2);
#pragma unroll
    for (int r = 0; r < 4; ++r) {
        int row0 = row0base + r, row1 = row0 + 16;
        float v00 = acc00[r] + b0, v01 = acc01[r] + b1;
        float v10 = acc10[r] + b0, v11 = acc11[r] + b1;
        if (row0 < N) {
            outb[(size_t)row0 * 128 + c0] = f2bf(v00);
            outb[(size_t)row0 * 128 + c1] = f2bf(v01);
            sum0 += v00; sq0 += v00 * v00; sum1 += v01; sq1 += v01 * v01;
        }
        if (row1 < N) {
            outb[(size_t)row1 * 128 + c0] = f2bf(v10);
            outb[(size_t)row1 * 128 + c1] = f2bf(v11);
            sum0 += v10; sq0 += v10 * v10; sum1 += v11; sq1 += v11 * v11;
        }
    }
#pragma unroll
    for (int m = 16; m < 64; m <<= 1) {
        sum0 += __shfl_xor(sum0, m); sq0 += __shfl_xor(sq0, m);
        sum1 += __shfl_xor(sum1, m); sq1 += __shfl_xor(sq1, m);
    }
    if (lane < 16) {
        float* st = stats8out + (blockIdx.x & 7) * 256;
        atomicAdd(&st[c0], sum0);
        atomicAdd(&st[128 + c0], sq0);
        atomicAdd(&st[c1], sum1);
        atomicAdd(&st[128 + c1], sq1);
    }
}

// ---------------- BN finalize from 8 sliced stat buffers ----------------
__global__ void bn_finalize8_k(const float* __restrict__ g, const float* __restrict__ be,
                               const float* __restrict__ stats8, float* __restrict__ sfin, int N) {
    int c = threadIdx.x;
    if (c < 128) {
        float s = 0.f, s2 = 0.f;
#pragma unroll
        for (int k = 0; k < 8; ++k) { s += stats8[k * 256 + c]; s2 += stats8[k * 256 + 128 + c]; }
        float mu = s / (float)N;
        float var = s2 / (float)N - mu * mu;
        float sc = g[c] * rsqrtf(var + BN_EPS);
        sfin[c] = sc;
        sfin[128 + c] = be[c] - mu * sc;
    }
}

// ---------------- BN apply + ReLU + bf16 in-place + p = h.Wl2 ----------------
__global__ void bn_apply_p_k(unsigned short* __restrict__ hb, const float* __restrict__ sfin,
                             const float* __restrict__ Wl2, float* __restrict__ p, int N) {
    const int lane = threadIdx.x & 63;
    const int n = (int)((blockIdx.x * (long long)blockDim.x + threadIdx.x) >> 6);
    if (n >= N) return;
    const float2 sc = ((const float2*)sfin)[lane];
    const float2 sh = ((const float2*)(sfin + 128))[lane];
    const float2 w  = ((const float2*)Wl2)[lane];
    unsigned int u = ((unsigned int*)(hb + (size_t)n * 128))[lane];
    float vx = fmaxf(bflo(u) * sc.x + sh.x, 0.f);
    float vy = fmaxf(bfhi(u) * sc.y + sh.y, 0.f);
    ((unsigned int*)(hb + (size_t)n * 128))[lane] = (unsigned int)f2bf(vx) | ((unsigned int)f2bf(vy) << 16);
    float s = vx * w.x + vy * w.y;
#pragma unroll
    for (int o = 32; o; o >>= 1) s += __shfl_down(s, o);
    if (lane == 0) p[n] = s;
}

// ---------------- layer 2 final ----------------
__global__ void layer2_final_k(const unsigned short* __restrict__ hb, const float* __restrict__ p,
                               const int* __restrict__ csr, const int* __restrict__ off,
                               const int* __restrict__ endp, const float* __restrict__ inv,
                               const float* __restrict__ Wr2, const float* __restrict__ bl2,
                               const float* __restrict__ wF, const float* __restrict__ bF,
                               float* __restrict__ out, int N) {
    const int lane = threadIdx.x & 63;
    const int n = (int)((blockIdx.x * (long long)blockDim.x + threadIdx.x) >> 6);
    if (n >= N) return;
    float2 w = ((const float2*)Wr2)[lane];
    unsigned int u = ((const unsigned int*)(hb + (size_t)n * 128))[lane];
    float dotp = bflo(u) * w.x + bfhi(u) * w.y;
    float ps = 0.f;
    const int o = off[n], e_end = endp[n];
    for (int e = o + lane; e < e_end; e += 64) ps += p[csr[e]];
    float s = dotp + ps * inv[n];
#pragma unroll
    for (int ow = 32; ow; ow >>= 1) s += __shfl_down(s, ow);
    if (lane == 0) {
        float z = (s + bl2[0]) * wF[0] + bF[0];
        out[n] = 1.f / (1.f + expf(-z));
    }
}

extern "C" void kernel_launch(void* const* d_in, const int* in_sizes, int n_in,
                              void* d_out, int out_size, void* d_ws, size_t ws_size,
                              hipStream_t stream) {
    const float* x   = (const float*)d_in[0];
    const int*   ei  = (const int*)d_in[1];
    const int E = in_sizes[1] / 2;
    const int N = in_sizes[0] / 64;
    const int* src = ei;
    const int* dst = ei + E;
    const float* Wl0 = (const float*)d_in[2];
    const float* bl0 = (const float*)d_in[3];
    const float* Wr0 = (const float*)d_in[4];
    const float* Wl1 = (const float*)d_in[5];
    const float* bl1 = (const float*)d_in[6];
    const float* Wr1 = (const float*)d_in[7];
    const float* Wl2 = (const float*)d_in[8];
    const float* bl2 = (const float*)d_in[9];
    const float* Wr2 = (const float*)d_in[10];
    const float* g0  = (const float*)d_in[11];
    const float* be0 = (const float*)d_in[12];
    const float* g1  = (const float*)d_in[13];
    const float* be1 = (const float*)d_in[14];
    const float* wF  = (const float*)d_in[15];
    const float* bF  = (const float*)d_in[16];

    char* wp = (char*)d_ws;
    unsigned short* h0   = (unsigned short*)wp;  wp += (size_t)N * 128 * 2;  // layer-0 out bf16 (pre-BN)
    unsigned short* h1   = (unsigned short*)wp;  wp += (size_t)N * 128 * 2;  // layer-1 out bf16
    unsigned short* xb   = (unsigned short*)wp;  wp += (size_t)N * 64 * 2;   // x bf16
    int*   cnt    = (int*)wp;    wp += (size_t)N * 4;
    int*   off    = (int*)wp;    wp += (size_t)N * 4;
    int*   cursor = (int*)wp;    wp += (size_t)N * 4;
    float* inv    = (float*)wp;  wp += (size_t)N * 4;
    int*   csr    = (int*)wp;    wp += (size_t)E * 4;
    uint2* ebuf   = (uint2*)wp;  wp += (size_t)E * 8;   // bucketed (src,dst) pairs
    float* stats8a = (float*)wp; wp += 2048 * 4;
    float* stats8b = (float*)wp; wp += 2048 * 4;
    float* sfin1   = (float*)wp; wp += 256 * 4;
    int*   bsum    = (int*)wp;   wp += 64 * 4;
    int*   bbase   = (int*)wp;   wp += 16 * 4;          // [9]
    int*   bcur    = (int*)wp;   wp += 16 * 4;          // [8]
    unsigned short* wf0 = (unsigned short*)wp; wp += 8 * 4 * 64 * 8 * 2;
    unsigned short* wf1 = (unsigned short*)wp; wp += 8 * 8 * 64 * 8 * 2;
    float* p = (float*)cnt;   // alias: cnt dead after scan/bucketize
    float* out = (float*)d_out;

    const int gemm_grid = (N + 31) / 32;
    const int wave_grid = (N + 3) / 4;
    const int nb = (N + SCAN_CHUNK - 1) / SCAN_CHUNK;
    const int nper = (N + 7) / 8;
    const int nchunks = (E + BCHUNK - 1) / BCHUNK;

    // ---- prep: weights, x->bf16, zero stats
    wfrag_build_k<<<(8 * 4 * 64 + 255) / 256, 256, 0, stream>>>(Wl0, Wr0, 64, 4, wf0);
    wfrag_build_k<<<(8 * 8 * 64 + 255) / 256, 256, 0, stream>>>(Wl1, Wr1, 128, 8, wf1);
    to_bf16_k<<<(N * 16 + 255) / 256, 256, 0, stream>>>(x, xb, N * 16);
    hipMemsetAsync(stats8a, 0, (2048 + 2048) * sizeof(float), stream);

    // ---- CSR build (bucketized)
    hipMemsetAsync(cnt, 0, (size_t)N * sizeof(int), stream);
    count_edges_sliced_k<<<2048, 256, 0, stream>>>(dst, E, cnt, nper);
    block_sum_k<<<nb, 256, 0, stream>>>(cnt, N, bsum);
    scan_write_k<<<nb, 256, 0, stream>>>(cnt, bsum, nb, N, off, cursor, inv);
    bucket_base_k<<<1, 16, 0, stream>>>(off, N, E, nper, bbase, bcur);
    bucketize_k<<<nchunks, 256, 0, stream>>>(src, dst, E, nper, bcur, ebuf);
    csr_fill_bucketed_k<<<2048, 256, 0, stream>>>(ebuf, bbase, cursor, csr);

    // ---- layer 0: xb -> h0 (raw, pre-BN)
    fused_sage_k<64, false><<<gemm_grid, 256, 0, stream>>>(
        xb, xb, csr, off, cursor, inv, wf0, bl0, nullptr, nullptr, nullptr, h0, stats8a, N);

    // ---- layer 1: h0 -> h1, BN0+ReLU applied on the fly (sfin0 from stats8a per block)
    fused_sage_k<128, true><<<gemm_grid, 256, 0, stream>>>(
        h0, h0, csr, off, cursor, inv, wf1, bl1, g0, be0, stats8a, h1, stats8b, N);

    // ---- BN1 finalize + apply + p = relu(bn(h1)).Wl2
    bn_finalize8_k<<<1, 128, 0, stream>>>(g1, be1, stats8b, sfin1, N);
    bn_apply_p_k<<<wave_grid, 256, 0, stream>>>(h1, sfin1, Wl2, p, N);

    // ---- layer 2 via scalar trick
    layer2_final_k<<<wave_grid, 256, 0, stream>>>(h1, p, csr, off, cursor, inv,
                                                  Wr2, bl2, wF, bF, out, N);
}

// Round 11
// 381.633 us; speedup vs baseline: 1.2484x; 1.0261x over previous
//
#include <hip/hip_runtime.h>
#include <math.h>

#define BN_EPS 1e-5f
#define SCAN_CHUNK 4096
#define BCHUNK 2048

typedef __attribute__((ext_vector_type(8))) short bf16x8;
typedef __attribute__((ext_vector_type(4))) float f32x4;

// RNE fp32 -> bf16 (bit pattern)
__device__ __forceinline__ unsigned short f2bf(float f) {
    unsigned int u = __float_as_uint(f);
    u = (u + 0x7fffu + ((u >> 16) & 1u)) >> 16;
    return (unsigned short)u;
}
__device__ __forceinline__ float bflo(unsigned int u) { return __uint_as_float(u << 16); }
__device__ __forceinline__ float bfhi(unsigned int u) { return __uint_as_float(u & 0xffff0000u); }

// accumulate 8 bf16 (one uint4), optionally BN affine + ReLU per element first
template<bool BNIN>
__device__ __forceinline__ void accv8(uint4 v, const float* sc, const float* sh, float* a) {
    unsigned int w[4] = {v.x, v.y, v.z, v.w};
#pragma unroll
    for (int j = 0; j < 4; ++j) {
        float lo = bflo(w[j]), hi = bfhi(w[j]);
        if constexpr (BNIN) {
            a[2 * j]     += fmaxf(lo * sc[2 * j]     + sh[2 * j],     0.f);
            a[2 * j + 1] += fmaxf(hi * sc[2 * j + 1] + sh[2 * j + 1], 0.f);
        } else {
            a[2 * j]     += lo;
            a[2 * j + 1] += hi;
        }
    }
}

// ---------------- fp32 -> bf16 bulk convert ----------------
__global__ void to_bf16_k(const float* __restrict__ in, unsigned short* __restrict__ out, int n4) {
    int i = blockIdx.x * blockDim.x + threadIdx.x;
    if (i >= n4) return;
    float4 v = ((const float4*)in)[i];
    ((ushort4*)out)[i] = make_ushort4(f2bf(v.x), f2bf(v.y), f2bf(v.z), f2bf(v.w));
}

// ---------------- hierarchical scan helpers ----------------
__device__ __forceinline__ int wave_incl_scan(int v, int lane) {
#pragma unroll
    for (int d = 1; d < 64; d <<= 1) {
        int u = __shfl_up(v, d);
        if (lane >= d) v += u;
    }
    return v;
}

__global__ void block_sum_k(const int* __restrict__ cnt, int N, int* __restrict__ bsum) {
    const int t = threadIdx.x;
    const int base = blockIdx.x * SCAN_CHUNK;
    int s = 0;
    for (int i = t; i < SCAN_CHUNK; i += 256) {
        int idx = base + i;
        if (idx < N) s += cnt[idx];
    }
    const int lane = t & 63, wid = t >> 6;
#pragma unroll
    for (int d = 32; d; d >>= 1) s += __shfl_down(s, d);
    __shared__ int ws[4];
    if (lane == 0) ws[wid] = s;
    __syncthreads();
    if (t == 0) bsum[blockIdx.x] = ws[0] + ws[1] + ws[2] + ws[3];
}

// per-chunk local scan + inline exclusive scan of bsum; writes off/cursor/inv
__global__ void scan_write_k(const int* __restrict__ cnt, const int* __restrict__ bsum, int nb,
                             int N, int* __restrict__ off, int* __restrict__ cursor,
                             float* __restrict__ inv) {
    const int t = threadIdx.x;
    __shared__ int ws[4];
    __shared__ int base_s;
    if (t < 64) {
        int v = (t < nb) ? bsum[t] : 0;
        int incl = wave_incl_scan(v, t);
        if (t == blockIdx.x) base_s = incl - v;
    }
    const int base = blockIdx.x * SCAN_CHUNK;
    const int idx0 = base + t * 16;
    int pre[16];
    int s = 0;
#pragma unroll
    for (int j = 0; j < 16; ++j) {
        int i = idx0 + j;
        int c = (i < N) ? cnt[i] : 0;
        pre[j] = s;
        s += c;
    }
    const int lane = t & 63, wid = t >> 6;
    int incl = wave_incl_scan(s, lane);
    if (lane == 63) ws[wid] = incl;
    __syncthreads();
    if (t == 0) {
        int a = 0;
#pragma unroll
        for (int w = 0; w < 4; ++w) { int tmp = ws[w]; ws[w] = a; a += tmp; }
    }
    __syncthreads();
    const int tbase = base_s + (incl - s) + ws[wid];
#pragma unroll
    for (int j = 0; j < 16; ++j) {
        int i = idx0 + j;
        if (i < N) {
            int c = cnt[i];
            int o = tbase + pre[j];
            off[i] = o;
            cursor[i] = o;
            inv[i] = 1.0f / fmaxf((float)c, 1.0f);
        }
    }
}

// ---------------- bucket cursor init (fixed bases with slack) ----------------
__global__ void bucket_init_k(int* __restrict__ bcur, int cap) {
    int b = threadIdx.x;
    if (b < 8) bcur[b] = b * cap;
}

// ---------------- bucketize: partition edge list into 8 dst-range buckets ----------------
// LDS-staged so global writes are coalesced segment flushes. ebuf[i] = (src, dst).
__global__ void bucketize_k(const int* __restrict__ src, const int* __restrict__ dst,
                            int E, int nper, int* __restrict__ bcur, uint2* __restrict__ ebuf) {
    __shared__ int hist[8], lofs[8], gofs[8], cpos[8];
    __shared__ uint2 buf[BCHUNK];
    const int t = threadIdx.x;
    const int base = blockIdx.x * BCHUNK;
    if (base >= E) return;
    const int chunk = min(BCHUNK, E - base);

    if (t < 8) hist[t] = 0;
    __syncthreads();

    int my_d[8], my_s[8], my_b[8];
#pragma unroll
    for (int j = 0; j < 8; ++j) {
        int e = base + j * 256 + t;
        if (j * 256 + t < chunk) {
            my_d[j] = dst[e];
            my_s[j] = src[e];
            my_b[j] = my_d[j] / nper;
            atomicAdd(&hist[my_b[j]], 1);
        } else my_b[j] = -1;
    }
    __syncthreads();
    if (t == 0) {
        int a = 0;
#pragma unroll
        for (int b = 0; b < 8; ++b) { lofs[b] = a; cpos[b] = a; a += hist[b]; }
    }
    __syncthreads();
    if (t < 8) gofs[t] = hist[t] ? atomicAdd(&bcur[t], hist[t]) : 0;
    __syncthreads();
#pragma unroll
    for (int j = 0; j < 8; ++j) {
        if (my_b[j] >= 0) {
            int pos = atomicAdd(&cpos[my_b[j]], 1);
            buf[pos] = make_uint2((unsigned)my_s[j], (unsigned)my_d[j]);
        }
    }
    __syncthreads();
    for (int i = t; i < chunk; i += 256) {
        int b = 0;
#pragma unroll
        for (int bb = 1; bb < 8; ++bb) if (i >= lofs[bb]) b = bb;
        ebuf[gofs[b] + (i - lofs[b])] = buf[i];
    }
}

// ---------------- degree count from bucketed edges (slice-local in one XCD L2) ----------
__global__ void count_ebuf_k(const uint2* __restrict__ ebuf, const int* __restrict__ bcur,
                             int cap, int* __restrict__ cnt) {
    const int s = blockIdx.x & 7;
    const int g = blockIdx.x >> 3;
    const int ng = gridDim.x >> 3;
    const int lo = s * cap, hi = bcur[s];
    for (int i = lo + g * blockDim.x + threadIdx.x; i < hi; i += ng * blockDim.x)
        atomicAdd(&cnt[(int)ebuf[i].y], 1);
}

// ---------------- CSR fill from buckets: slice s works entirely in one XCD's L2 ----------
__global__ void csr_fill_bucketed_k(const uint2* __restrict__ ebuf, const int* __restrict__ bcur,
                                    int cap, int* __restrict__ cursor, int* __restrict__ csr) {
    const int s = blockIdx.x & 7;
    const int g = blockIdx.x >> 3;
    const int ng = gridDim.x >> 3;
    const int lo = s * cap, hi = bcur[s];
    for (int i = lo + g * blockDim.x + threadIdx.x; i < hi; i += ng * blockDim.x) {
        uint2 v = ebuf[i];
        int pos = atomicAdd(&cursor[(int)v.y], 1);
        csr[pos] = (int)v.x;
    }
}

// ---------------- weight pre-pack into MFMA B-fragment order (bf16) ----------------
__global__ void wfrag_build_k(const float* __restrict__ Wl, const float* __restrict__ Wr,
                              int CIN, int KIT, unsigned short* __restrict__ wf) {
    int t = blockIdx.x * blockDim.x + threadIdx.x;
    int lane = t & 63;
    int q = t >> 6;
    if (q >= 8 * KIT) return;
    int kit = q % KIT;
    int ct = q / KIT;
    int col = ct * 16 + (lane & 15);
    bf16x8 v;
#pragma unroll
    for (int j = 0; j < 8; ++j) {
        int kg = kit * 32 + ((lane >> 4) << 3) + j;
        float f = (kg < CIN) ? Wl[(size_t)kg * 128 + col] : Wr[(size_t)(kg - CIN) * 128 + col];
        v[j] = (short)f2bf(f);
    }
    ((bf16x8*)wf)[q * 64 + lane] = v;
}

// ---------------- fused [BN0-on-read] gather-mean + MFMA gemm + BN stats ----------------
// outb[32x128] = bf16([mean_agg(f(feat)) | f(xin)] @ [Wl;Wr] + bl),
// f = identity (BNIN=false) or relu(bn(.)). Gather is uint4/lane: one wave VMEM
// instruction fetches 4 (CIN=128) or 8 (CIN=64) neighbor rows at once.
template<int CIN, bool BNIN>
__launch_bounds__(256)
__global__ void fused_sage_k(const unsigned short* __restrict__ feat,
                             const unsigned short* __restrict__ xin,
                             const int* __restrict__ csr, const int* __restrict__ off,
                             const int* __restrict__ endp, const float* __restrict__ inv,
                             const unsigned short* __restrict__ wfrag,
                             const float* __restrict__ bl,
                             const float* __restrict__ g, const float* __restrict__ be,
                             const float* __restrict__ stats8in,
                             unsigned short* __restrict__ outb,
                             float* __restrict__ stats8out, int N) {
    constexpr int KT = 2 * CIN;
    constexpr int KIT = KT / 32;
    __shared__ unsigned short sA[32 * KT];   // [row][k] bf16, XOR-swizzled by (row&7)<<4 bytes
    __shared__ float sfinS[256];             // scale[128], shift[128] (BNIN only)

    const int t = threadIdx.x;
    const int lane = t & 63, wave = t >> 6;
    const int rowbase = blockIdx.x * 32;

    if constexpr (BNIN) {
        if (t < 128) {
            float s = 0.f, s2 = 0.f;
#pragma unroll
            for (int k = 0; k < 8; ++k) { s += stats8in[k * 256 + t]; s2 += stats8in[k * 256 + 128 + t]; }
            float mu = s / (float)N;
            float var = s2 / (float)N - mu * mu;
            float sc = g[t] * rsqrtf(var + BN_EPS);
            sfinS[t] = sc;
            sfinS[128 + t] = be[t] - mu * sc;
        }
        __syncthreads();
    }

    // ---- xin half: bf16 copy (+ optional BN affine + ReLU), 16B chunks
    constexpr int CH8 = CIN / 8;
    for (int i = t; i < 32 * CH8; i += 256) {
        int r = i / CH8, q = i % CH8;
        if (rowbase + r < N) {
            uint4 v = ((const uint4*)(xin + (size_t)(rowbase + r) * CIN))[q];
            if constexpr (BNIN) {
                unsigned int w[4] = {v.x, v.y, v.z, v.w};
#pragma unroll
                for (int j = 0; j < 4; ++j) {
                    int c = q * 8 + 2 * j;
                    float lo = fmaxf(bflo(w[j]) * sfinS[c]     + sfinS[128 + c],     0.f);
                    float hi = fmaxf(bfhi(w[j]) * sfinS[c + 1] + sfinS[128 + c + 1], 0.f);
                    w[j] = (unsigned int)f2bf(lo) | ((unsigned int)f2bf(hi) << 16);
                }
                v = make_uint4(w[0], w[1], w[2], w[3]);
            }
            int byte = ((r * KT + CIN + q * 8) * 2) ^ ((r & 7) << 4);
            *(uint4*)((char*)sA + byte) = v;
        }
    }

    // ---- agg half: uint4 gather. Groups of lanes each own a neighbor subset.
    // CIN=128: 4 groups x 16 lanes (uint4 col c4 covers bf16 cols [8c4,8c4+8))
    // CIN=64 : 8 groups x  8 lanes
    constexpr int GSH = (CIN == 128) ? 4 : 3;           // log2(lanes per row)
    constexpr int NG  = 64 >> GSH;                      // neighbor groups: 4 or 8
    const int g2 = lane >> GSH;
    const int c4 = lane & ((1 << GSH) - 1);
    constexpr int ROWU = CIN / 8;                       // uint4 per feature row

    float scv[8], shv[8];
    if constexpr (BNIN) {
#pragma unroll
        for (int j = 0; j < 8; ++j) {
            scv[j] = sfinS[8 * c4 + j];
            shv[j] = sfinS[128 + 8 * c4 + j];
        }
    }

#pragma unroll
    for (int rr = 0; rr < 8; ++rr) {
        int r = wave * 8 + rr;
        int n = rowbase + r;
        if (n < N) {
            const int o = off[n], eend = endp[n];
            float a[8] = {0.f, 0.f, 0.f, 0.f, 0.f, 0.f, 0.f, 0.f};
            int e = o + g2;
            for (; e + NG < eend; e += 2 * NG) {
                int i0 = csr[e], i1 = csr[e + NG];
                uint4 v0 = ((const uint4*)(feat + (size_t)i0 * CIN))[c4];
                uint4 v1 = ((const uint4*)(feat + (size_t)i1 * CIN))[c4];
                accv8<BNIN>(v0, scv, shv, a);
                accv8<BNIN>(v1, scv, shv, a);
            }
            if (e < eend) {
                uint4 v0 = ((const uint4*)(feat + (size_t)csr[e] * CIN))[c4];
                accv8<BNIN>(v0, scv, shv, a);
            }
            // reduce across neighbor groups
#pragma unroll
            for (int j = 0; j < 8; ++j) {
                if constexpr (CIN == 64) a[j] += __shfl_xor(a[j], 8);
                a[j] += __shfl_xor(a[j], 16);
                a[j] += __shfl_xor(a[j], 32);
            }
            if (g2 == 0) {
                float iv = inv[n];
                unsigned int pw[4];
#pragma unroll
                for (int j = 0; j < 4; ++j)
                    pw[j] = (unsigned int)f2bf(a[2 * j] * iv) |
                            ((unsigned int)f2bf(a[2 * j + 1] * iv) << 16);
                int byte = ((r * KT + 8 * c4) * 2) ^ ((r & 7) << 4);
                *(uint4*)((char*)sA + byte) = make_uint4(pw[0], pw[1], pw[2], pw[3]);
            }
        }
    }
    __syncthreads();

    // ---- MFMA K-loop
    f32x4 acc00 = {0.f,0.f,0.f,0.f}, acc01 = acc00, acc10 = acc00, acc11 = acc00;
    const int koff = (lane >> 4) << 4;
    const int swz = (lane & 7) << 4;
    const int base0 = (lane & 15) * KT * 2 + koff;
    const int base1 = (16 + (lane & 15)) * KT * 2 + koff;
    const bf16x8* wf8 = (const bf16x8*)wfrag;
    const int bq0 = (wave * 2 + 0) * KIT;
    const int bq1 = (wave * 2 + 1) * KIT;

#pragma unroll
    for (int kit = 0; kit < KIT; ++kit) {
        bf16x8 fa0 = *(const bf16x8*)((const char*)sA + ((base0 + kit * 64) ^ swz));
        bf16x8 fa1 = *(const bf16x8*)((const char*)sA + ((base1 + kit * 64) ^ swz));
        bf16x8 fb0 = wf8[(bq0 + kit) * 64 + lane];
        bf16x8 fb1 = wf8[(bq1 + kit) * 64 + lane];
        acc00 = __builtin_amdgcn_mfma_f32_16x16x32_bf16(fa0, fb0, acc00, 0, 0, 0);
        acc01 = __builtin_amdgcn_mfma_f32_16x16x32_bf16(fa0, fb1, acc01, 0, 0, 0);
        acc10 = __builtin_amdgcn_mfma_f32_16x16x32_bf16(fa1, fb0, acc10, 0, 0, 0);
        acc11 = __builtin_amdgcn_mfma_f32_16x16x32_bf16(fa1, fb1, acc11, 0, 0, 0);
    }

    // ---- epilogue: bf16 store + fp32 col stats. C/D layout col=lane&15, row=(lane>>4)*4+reg.
    const int c0 = wave * 32 + (lane & 15);
    const int c1 = c0 + 16;
    const float b0 = bl[c0], b1 = bl[c1];
    float sum0 = 0.f, sq0 = 0.f, sum1 = 0.f, sq1 = 0.f;
    const int row0base = rowbase + ((lane >> 4) << 2);
#pragma unroll
    for (int r = 0; r < 4; ++r) {
        int row0 = row0base + r, row1 = row0 + 16;
        float v00 = acc00[r] + b0, v01 = acc01[r] + b1;
        float v10 = acc10[r] + b0, v11 = acc11[r] + b1;
        if (row0 < N) {
            outb[(size_t)row0 * 128 + c0] = f2bf(v00);
            outb[(size_t)row0 * 128 + c1] = f2bf(v01);
            sum0 += v00; sq0 += v00 * v00; sum1 += v01; sq1 += v01 * v01;
        }
        if (row1 < N) {
            outb[(size_t)row1 * 128 + c0] = f2bf(v10);
            outb[(size_t)row1 * 128 + c1] = f2bf(v11);
            sum0 += v10; sq0 += v10 * v10; sum1 += v11; sq1 += v11 * v11;
        }
    }
#pragma unroll
    for (int m = 16; m < 64; m <<= 1) {
        sum0 += __shfl_xor(sum0, m); sq0 += __shfl_xor(sq0, m);
        sum1 += __shfl_xor(sum1, m); sq1 += __shfl_xor(sq1, m);
    }
    if (lane < 16) {
        float* st = stats8out + (blockIdx.x & 7) * 256;
        atomicAdd(&st[c0], sum0);
        atomicAdd(&st[128 + c0], sq0);
        atomicAdd(&st[c1], sum1);
        atomicAdd(&st[128 + c1], sq1);
    }
}

// ---------------- BN finalize from 8 sliced stat buffers ----------------
__global__ void bn_finalize8_k(const float* __restrict__ g, const float* __restrict__ be,
                               const float* __restrict__ stats8, float* __restrict__ sfin, int N) {
    int c = threadIdx.x;
    if (c < 128) {
        float s = 0.f, s2 = 0.f;
#pragma unroll
        for (int k = 0; k < 8; ++k) { s += stats8[k * 256 + c]; s2 += stats8[k * 256 + 128 + c]; }
        float mu = s / (float)N;
        float var = s2 / (float)N - mu * mu;
        float sc = g[c] * rsqrtf(var + BN_EPS);
        sfin[c] = sc;
        sfin[128 + c] = be[c] - mu * sc;
    }
}

// ---------------- BN apply + ReLU + bf16 in-place + p = h.Wl2 ----------------
__global__ void bn_apply_p_k(unsigned short* __restrict__ hb, const float* __restrict__ sfin,
                             const float* __restrict__ Wl2, float* __restrict__ p, int N) {
    const int lane = threadIdx.x & 63;
    const int n = (int)((blockIdx.x * (long long)blockDim.x + threadIdx.x) >> 6);
    if (n >= N) return;
    const float2 sc = ((const float2*)sfin)[lane];
    const float2 sh = ((const float2*)(sfin + 128))[lane];
    const float2 w  = ((const float2*)Wl2)[lane];
    unsigned int u = ((unsigned int*)(hb + (size_t)n * 128))[lane];
    float vx = fmaxf(bflo(u) * sc.x + sh.x, 0.f);
    float vy = fmaxf(bfhi(u) * sc.y + sh.y, 0.f);
    ((unsigned int*)(hb + (size_t)n * 128))[lane] = (unsigned int)f2bf(vx) | ((unsigned int)f2bf(vy) << 16);
    float s = vx * w.x + vy * w.y;
#pragma unroll
    for (int o = 32; o; o >>= 1) s += __shfl_down(s, o);
    if (lane == 0) p[n] = s;
}

// ---------------- layer 2 final ----------------
__global__ void layer2_final_k(const unsigned short* __restrict__ hb, const float* __restrict__ p,
                               const int* __restrict__ csr, const int* __restrict__ off,
                               const int* __restrict__ endp, const float* __restrict__ inv,
                               const float* __restrict__ Wr2, const float* __restrict__ bl2,
                               const float* __restrict__ wF, const float* __restrict__ bF,
                               float* __restrict__ out, int N) {
    const int lane = threadIdx.x & 63;
    const int n = (int)((blockIdx.x * (long long)blockDim.x + threadIdx.x) >> 6);
    if (n >= N) return;
    float2 w = ((const float2*)Wr2)[lane];
    unsigned int u = ((const unsigned int*)(hb + (size_t)n * 128))[lane];
    float dotp = bflo(u) * w.x + bfhi(u) * w.y;
    float ps = 0.f;
    const int o = off[n], e_end = endp[n];
    for (int e = o + lane; e < e_end; e += 64) ps += p[csr[e]];
    float s = dotp + ps * inv[n];
#pragma unroll
    for (int ow = 32; ow; ow >>= 1) s += __shfl_down(s, ow);
    if (lane == 0) {
        float z = (s + bl2[0]) * wF[0] + bF[0];
        out[n] = 1.f / (1.f + expf(-z));
    }
}

extern "C" void kernel_launch(void* const* d_in, const int* in_sizes, int n_in,
                              void* d_out, int out_size, void* d_ws, size_t ws_size,
                              hipStream_t stream) {
    const float* x   = (const float*)d_in[0];
    const int*   ei  = (const int*)d_in[1];
    const int E = in_sizes[1] / 2;
    const int N = in_sizes[0] / 64;
    const int* src = ei;
    const int* dst = ei + E;
    const float* Wl0 = (const float*)d_in[2];
    const float* bl0 = (const float*)d_in[3];
    const float* Wr0 = (const float*)d_in[4];
    const float* Wl1 = (const float*)d_in[5];
    const float* bl1 = (const float*)d_in[6];
    const float* Wr1 = (const float*)d_in[7];
    const float* Wl2 = (const float*)d_in[8];
    const float* bl2 = (const float*)d_in[9];
    const float* Wr2 = (const float*)d_in[10];
    const float* g0  = (const float*)d_in[11];
    const float* be0 = (const float*)d_in[12];
    const float* g1  = (const float*)d_in[13];
    const float* be1 = (const float*)d_in[14];
    const float* wF  = (const float*)d_in[15];
    const float* bF  = (const float*)d_in[16];

    const int cap = E / 4;                              // per-bucket capacity (2x mean)

    char* wp = (char*)d_ws;
    unsigned short* h0   = (unsigned short*)wp;  wp += (size_t)N * 128 * 2;  // layer-0 out bf16 (pre-BN)
    unsigned short* h1   = (unsigned short*)wp;  wp += (size_t)N * 128 * 2;  // layer-1 out bf16
    unsigned short* xb   = (unsigned short*)wp;  wp += (size_t)N * 64 * 2;   // x bf16
    int*   cnt    = (int*)wp;    wp += (size_t)N * 4;
    int*   off    = (int*)wp;    wp += (size_t)N * 4;
    int*   cursor = (int*)wp;    wp += (size_t)N * 4;
    float* inv    = (float*)wp;  wp += (size_t)N * 4;
    int*   csr    = (int*)wp;    wp += (size_t)E * 4;
    uint2* ebuf   = (uint2*)wp;  wp += (size_t)8 * cap * 8;  // bucketed (src,dst), fixed bases
    float* stats8a = (float*)wp; wp += 2048 * 4;
    float* stats8b = (float*)wp; wp += 2048 * 4;
    float* sfin1   = (float*)wp; wp += 256 * 4;
    int*   bsum    = (int*)wp;   wp += 64 * 4;
    int*   bcur    = (int*)wp;   wp += 16 * 4;
    unsigned short* wf0 = (unsigned short*)wp; wp += 8 * 4 * 64 * 8 * 2;
    unsigned short* wf1 = (unsigned short*)wp; wp += 8 * 8 * 64 * 8 * 2;
    float* p = (float*)cnt;   // alias: cnt dead after scan
    float* out = (float*)d_out;

    const int gemm_grid = (N + 31) / 32;
    const int wave_grid = (N + 3) / 4;
    const int nb = (N + SCAN_CHUNK - 1) / SCAN_CHUNK;
    const int nper = (N + 7) / 8;
    const int nchunks = (E + BCHUNK - 1) / BCHUNK;

    // ---- prep: weights, x->bf16, zero stats
    wfrag_build_k<<<(8 * 4 * 64 + 255) / 256, 256, 0, stream>>>(Wl0, Wr0, 64, 4, wf0);
    wfrag_build_k<<<(8 * 8 * 64 + 255) / 256, 256, 0, stream>>>(Wl1, Wr1, 128, 8, wf1);
    to_bf16_k<<<(N * 16 + 255) / 256, 256, 0, stream>>>(x, xb, N * 16);
    hipMemsetAsync(stats8a, 0, (2048 + 2048) * sizeof(float), stream);
    hipMemsetAsync(cnt, 0, (size_t)N * sizeof(int), stream);

    // ---- CSR build: bucketize first, then slice-local count / scan / fill
    bucket_init_k<<<1, 8, 0, stream>>>(bcur, cap);
    bucketize_k<<<nchunks, 256, 0, stream>>>(src, dst, E, nper, bcur, ebuf);
    count_ebuf_k<<<2048, 256, 0, stream>>>(ebuf, bcur, cap, cnt);
    block_sum_k<<<nb, 256, 0, stream>>>(cnt, N, bsum);
    scan_write_k<<<nb, 256, 0, stream>>>(cnt, bsum, nb, N, off, cursor, inv);
    csr_fill_bucketed_k<<<2048, 256, 0, stream>>>(ebuf, bcur, cap, cursor, csr);

    // ---- layer 0: xb -> h0 (raw, pre-BN)
    fused_sage_k<64, false><<<gemm_grid, 256, 0, stream>>>(
        xb, xb, csr, off, cursor, inv, wf0, bl0, nullptr, nullptr, nullptr, h0, stats8a, N);

    // ---- layer 1: h0 -> h1, BN0+ReLU applied on the fly (sfin0 from stats8a per block)
    fused_sage_k<128, true><<<gemm_grid, 256, 0, stream>>>(
        h0, h0, csr, off, cursor, inv, wf1, bl1, g0, be0, stats8a, h1, stats8b, N);

    // ---- BN1 finalize + apply + p = relu(bn(h1)).Wl2
    bn_finalize8_k<<<1, 128, 0, stream>>>(g1, be1, stats8b, sfin1, N);
    bn_apply_p_k<<<wave_grid, 256, 0, stream>>>(h1, sfin1, Wl2, p, N);

    // ---- layer 2 via scalar trick
    layer2_final_k<<<wave_grid, 256, 0, stream>>>(h1, p, csr, off, cursor, inv,
                                                  Wr2, bl2, wF, bF, out, N);
}